// Round 1
// baseline (521.180 us; speedup 1.0000x reference)
//
#include <hip/hip_runtime.h>

#define P_TOT 1482625
#define BATCH 64
#define EMB 16
#define DFEAT 512
#define KCODE 512

// ---------------------------------------------------------------------------
// Kernel 1: encoder fc + VQ argmin + quantized + per-batch loss partial (fp32).
// grid = 64 blocks (one per batch row), 256 threads.
// ws: qws[64*16] fp32, loss_part[64] fp32.
// (unchanged — ~3 us, not on the critical path)
// ---------------------------------------------------------------------------
__global__ __launch_bounds__(256) void k_embed_vq(
    const float* __restrict__ feat,
    const float* __restrict__ fcw,
    const float* __restrict__ fcb,
    const float* __restrict__ cb,
    float* __restrict__ qws,
    float* __restrict__ loss_part)
{
    const int b   = blockIdx.x;
    const int tid = threadIdx.x;

    __shared__ float red[EMB][17];
    __shared__ float embed_s[EMB];
    __shared__ float dist_s[256];
    __shared__ int   idx_s[256];

    // embed[b][e] = dot(feat[b,:], fcw[e,:]) + fcb[e]
    {
        const int e = tid >> 4;       // 0..15
        const int c = tid & 15;       // chunk of 32 floats
        const float4* fp = (const float4*)(feat + b * DFEAT + c * 32);
        const float4* wp = (const float4*)(fcw  + e * DFEAT + c * 32);
        float acc = 0.f;
#pragma unroll
        for (int j = 0; j < 8; j++) {
            float4 f = fp[j], w = wp[j];
            acc += f.x * w.x + f.y * w.y + f.z * w.z + f.w * w.w;
        }
        red[e][c] = acc;
    }
    __syncthreads();
    if (tid < EMB) {
        float s = fcb[tid];
#pragma unroll
        for (int c = 0; c < 16; c++) s += red[tid][c];
        embed_s[tid] = s;
    }
    __syncthreads();

    float emb[EMB];
#pragma unroll
    for (int e = 0; e < EMB; e++) emb[e] = embed_s[e];

    // rank-equivalent distance: sum(c^2) - 2 e.c  (sum(e^2) is row-constant)
    float bestd = 1e30f;
    int   bestk = 0;
#pragma unroll
    for (int r = 0; r < 2; r++) {
        const int k = tid + r * 256;
        const float4* cp = (const float4*)(cb + k * EMB);
        float d = 0.f;
#pragma unroll
        for (int q = 0; q < 4; q++) {
            float4 cv = cp[q];
            d += cv.x * cv.x - 2.f * cv.x * emb[q * 4 + 0];
            d += cv.y * cv.y - 2.f * cv.y * emb[q * 4 + 1];
            d += cv.z * cv.z - 2.f * cv.z * emb[q * 4 + 2];
            d += cv.w * cv.w - 2.f * cv.w * emb[q * 4 + 3];
        }
        if (d < bestd) { bestd = d; bestk = k; }  // strict < => first-min kept
    }
    dist_s[tid] = bestd;
    idx_s[tid]  = bestk;
    __syncthreads();

    for (int s = 128; s > 0; s >>= 1) {
        if (tid < s) {
            float od = dist_s[tid + s];
            int   ok = idx_s[tid + s];
            if (od < dist_s[tid] || (od == dist_s[tid] && ok < idx_s[tid])) {
                dist_s[tid] = od;
                idx_s[tid]  = ok;
            }
        }
        __syncthreads();
    }

    if (tid == 0) {
        const int kb = idx_s[0];
        float l = 0.f;
#pragma unroll
        for (int e = 0; e < EMB; e++) {
            float qv = cb[kb * EMB + e];
            qws[b * EMB + e] = qv;        // forward(quantized_st) == quantized
            float dd = qv - embed_s[e];
            l += dd * dd;
        }
        loss_part[b] = l;
    }
}

// ---------------------------------------------------------------------------
// Kernel 2: gen = quantized @ Wgen ([64,16]x[16,P]) + loss finalize (fp32).
// RESTRUCTURED for occupancy/MLP:
//   - 512 consecutive columns per block (was 1024); thread owns 2 columns at
//     stride 64 (lane-contiguous dword coalescing preserved).
//   - per-thread register footprint halved: w0[16]+w1[16] = 32 VGPR target
//     ~60 total -> 8 waves/SIMD (was ~4): 2x store concurrency per CU.
//   - 2896 column-blocks = 11.3 blocks/CU: finer-grained tail balance.
//   - nontemporal stores: out is write-once, never re-read -> skip L2
//     retention (fill kernel behavior).
// qws still read with uniform addresses -> s_load -> SGPR-operand FMAs.
// ---------------------------------------------------------------------------
__global__ __launch_bounds__(256) void k_gen(
    const float* __restrict__ Wgen,
    const float* __restrict__ qws,
    const float* __restrict__ loss_part,
    float* __restrict__ out)
{
    if (blockIdx.x == 0) {
        if (threadIdx.x < 64) {
            float v = loss_part[threadIdx.x];
#pragma unroll
            for (int o = 32; o > 0; o >>= 1) v += __shfl_down(v, o, 64);
            if (threadIdx.x == 0)
                out[(size_t)BATCH * P_TOT] = 1.25f * v * (1.0f / 1024.0f);
        }
        return;
    }

    const int lane = threadIdx.x & 63;
    const int wv   = threadIdx.x >> 6;
    const int myc  = wv * 128 + lane;                 // + j*64, j<2
    const size_t col0 = (size_t)(blockIdx.x - 1) * 512;

    if (col0 + 512 <= (size_t)P_TOT) {
        // full block: no bounds checks
        const float* wp = Wgen + col0 + myc;
        float w0[EMB], w1[EMB];
#pragma unroll
        for (int e = 0; e < EMB; e++) {
            const float* we = wp + (size_t)e * P_TOT;
            w0[e] = we[0];
            w1[e] = we[64];
        }

        float* ob = out + col0 + myc;
#pragma unroll 2
        for (int b = 0; b < BATCH; b++) {
            const float* q = qws + b * EMB;           // uniform -> s_load
            float a0 = 0.f, a1 = 0.f;
#pragma unroll
            for (int e = 0; e < EMB; e++) {
                const float qe = q[e];
                a0 = fmaf(qe, w0[e], a0);
                a1 = fmaf(qe, w1[e], a1);
            }
            __builtin_nontemporal_store(a0, ob);
            __builtin_nontemporal_store(a1, ob + 64);
            ob += P_TOT;
        }
    } else {
        // tail block: per-column guard
#pragma unroll
        for (int j = 0; j < 2; j++) {
            const size_t c = col0 + myc + (size_t)j * 64;
            if (c < (size_t)P_TOT) {
                float wt[EMB];
#pragma unroll
                for (int e = 0; e < EMB; e++)
                    wt[e] = Wgen[(size_t)e * P_TOT + c];
                for (int b = 0; b < BATCH; b++) {
                    const float* q = qws + b * EMB;
                    float a = 0.f;
#pragma unroll
                    for (int e = 0; e < EMB; e++) a = fmaf(q[e], wt[e], a);
                    out[(size_t)b * P_TOT + c] = a;
                }
            }
        }
    }
}

extern "C" void kernel_launch(void* const* d_in, const int* in_sizes, int n_in,
                              void* d_out, int out_size, void* d_ws, size_t ws_size,
                              hipStream_t stream) {
    const float* feat = (const float*)d_in[0];
    const float* fcw  = (const float*)d_in[1];
    const float* fcb  = (const float*)d_in[2];
    const float* cb   = (const float*)d_in[3];
    const float* wgen = (const float*)d_in[4];
    float* out = (float*)d_out;

    float* qws   = (float*)d_ws;          // 1024 fp32
    float* lpart = qws + BATCH * EMB;     // 64 fp32

    k_embed_vq<<<BATCH, 256, 0, stream>>>(feat, fcw, fcb, cb, qws, lpart);

    const int colblocks = (P_TOT + 511) / 512;        // 2896
    k_gen<<<colblocks + 1, 256, 0, stream>>>(wgen, qws, lpart, out);
}

// Round 2
// 474.154 us; speedup vs baseline: 1.0992x; 1.0992x over previous
//
#include <hip/hip_runtime.h>

#define P_TOT 1482625
#define BATCH 64
#define EMB 16
#define DFEAT 512
#define KCODE 512

// ---------------------------------------------------------------------------
// Kernel 1: encoder fc + VQ argmin + quantized + per-batch loss partial (fp32).
// grid = 64 blocks (one per batch row), 256 threads.
// ws: qws[64*16] fp32, loss_part[64] fp32.  (~3 us, off critical path)
// ---------------------------------------------------------------------------
__global__ __launch_bounds__(256) void k_embed_vq(
    const float* __restrict__ feat,
    const float* __restrict__ fcw,
    const float* __restrict__ fcb,
    const float* __restrict__ cb,
    float* __restrict__ qws,
    float* __restrict__ loss_part)
{
    const int b   = blockIdx.x;
    const int tid = threadIdx.x;

    __shared__ float red[EMB][17];
    __shared__ float embed_s[EMB];
    __shared__ float dist_s[256];
    __shared__ int   idx_s[256];

    // embed[b][e] = dot(feat[b,:], fcw[e,:]) + fcb[e]
    {
        const int e = tid >> 4;       // 0..15
        const int c = tid & 15;       // chunk of 32 floats
        const float4* fp = (const float4*)(feat + b * DFEAT + c * 32);
        const float4* wp = (const float4*)(fcw  + e * DFEAT + c * 32);
        float acc = 0.f;
#pragma unroll
        for (int j = 0; j < 8; j++) {
            float4 f = fp[j], w = wp[j];
            acc += f.x * w.x + f.y * w.y + f.z * w.z + f.w * w.w;
        }
        red[e][c] = acc;
    }
    __syncthreads();
    if (tid < EMB) {
        float s = fcb[tid];
#pragma unroll
        for (int c = 0; c < 16; c++) s += red[tid][c];
        embed_s[tid] = s;
    }
    __syncthreads();

    float emb[EMB];
#pragma unroll
    for (int e = 0; e < EMB; e++) emb[e] = embed_s[e];

    // rank-equivalent distance: sum(c^2) - 2 e.c  (sum(e^2) is row-constant)
    float bestd = 1e30f;
    int   bestk = 0;
#pragma unroll
    for (int r = 0; r < 2; r++) {
        const int k = tid + r * 256;
        const float4* cp = (const float4*)(cb + k * EMB);
        float d = 0.f;
#pragma unroll
        for (int q = 0; q < 4; q++) {
            float4 cv = cp[q];
            d += cv.x * cv.x - 2.f * cv.x * emb[q * 4 + 0];
            d += cv.y * cv.y - 2.f * cv.y * emb[q * 4 + 1];
            d += cv.z * cv.z - 2.f * cv.z * emb[q * 4 + 2];
            d += cv.w * cv.w - 2.f * cv.w * emb[q * 4 + 3];
        }
        if (d < bestd) { bestd = d; bestk = k; }  // strict < => first-min kept
    }
    dist_s[tid] = bestd;
    idx_s[tid]  = bestk;
    __syncthreads();

    for (int s = 128; s > 0; s >>= 1) {
        if (tid < s) {
            float od = dist_s[tid + s];
            int   ok = idx_s[tid + s];
            if (od < dist_s[tid] || (od == dist_s[tid] && ok < idx_s[tid])) {
                dist_s[tid] = od;
                idx_s[tid]  = ok;
            }
        }
        __syncthreads();
    }

    if (tid == 0) {
        const int kb = idx_s[0];
        float l = 0.f;
#pragma unroll
        for (int e = 0; e < EMB; e++) {
            float qv = cb[kb * EMB + e];
            qws[b * EMB + e] = qv;        // forward(quantized_st) == quantized
            float dd = qv - embed_s[e];
            l += dd * dd;
        }
        loss_part[b] = l;
    }
}

// ---------------------------------------------------------------------------
// Kernel 2: gen = quantized @ Wgen ([64,16]x[16,P]) + loss finalize (fp32).
// Round-0 structure (1024 cols/block, 4 cols/thread, regular stores) RESTORED
// — round-1's nontemporal stores bypassed L2 write-combining on the 4B-aligned
// row bases and regressed 8%.
// NEW: software-pipelined q-loads. The per-b scalar load of q[b*16..] (~150cy
// K$ latency) was the only serial cost left on the critical path, 64x per
// wave. Prefetch q for b+1 into registers BEFORE the FMA block of b so the
// s_load latency hides under 128cy of FMA + 4 stores.
// ---------------------------------------------------------------------------
__global__ __launch_bounds__(256) void k_gen(
    const float* __restrict__ Wgen,
    const float* __restrict__ qws,
    const float* __restrict__ loss_part,
    float* __restrict__ out)
{
    if (blockIdx.x == 0) {
        if (threadIdx.x < 64) {
            float v = loss_part[threadIdx.x];
#pragma unroll
            for (int o = 32; o > 0; o >>= 1) v += __shfl_down(v, o, 64);
            if (threadIdx.x == 0)
                out[(size_t)BATCH * P_TOT] = 1.25f * v * (1.0f / 1024.0f);
        }
        return;
    }

    const int lane = threadIdx.x & 63;
    const int wv   = threadIdx.x >> 6;
    const int myc  = wv * 256 + lane;                 // + j*64, j<4
    const size_t col0 = (size_t)(blockIdx.x - 1) * 1024;

    if (col0 + 1024 <= (size_t)P_TOT) {
        // full block: no bounds checks
        const float* wp = Wgen + col0 + myc;
        float w[EMB][4];
#pragma unroll
        for (int e = 0; e < EMB; e++) {
            const float* we = wp + (size_t)e * P_TOT;
#pragma unroll
            for (int j = 0; j < 4; j++) w[e][j] = we[j * 64];
        }

        // prefetch q for b=0 (uniform address -> s_load)
        float qn[EMB];
#pragma unroll
        for (int e = 0; e < EMB; e++) qn[e] = qws[e];

        float* op = out + col0 + myc;
#pragma unroll 2
        for (int b = 0; b < BATCH; b++) {
            float qc[EMB];
#pragma unroll
            for (int e = 0; e < EMB; e++) qc[e] = qn[e];

            if (b + 1 < BATCH) {
                const float* q1 = qws + (b + 1) * EMB;   // uniform -> s_load
#pragma unroll
                for (int e = 0; e < EMB; e++) qn[e] = q1[e];
            }

            float acc[4] = {0.f, 0.f, 0.f, 0.f};
#pragma unroll
            for (int e = 0; e < EMB; e++) {
                const float qe = qc[e];
#pragma unroll
                for (int j = 0; j < 4; j++) acc[j] = fmaf(qe, w[e][j], acc[j]);
            }
            float* ob = op + (size_t)b * P_TOT;
#pragma unroll
            for (int j = 0; j < 4; j++) ob[j * 64] = acc[j];
        }
    } else {
        // tail block: per-column guard
#pragma unroll
        for (int j = 0; j < 4; j++) {
            const size_t c = col0 + myc + (size_t)j * 64;
            if (c < (size_t)P_TOT) {
                float w1[EMB];
#pragma unroll
                for (int e = 0; e < EMB; e++)
                    w1[e] = Wgen[(size_t)e * P_TOT + c];
                for (int b = 0; b < BATCH; b++) {
                    const float* q = qws + b * EMB;
                    float a = 0.f;
#pragma unroll
                    for (int e = 0; e < EMB; e++) a = fmaf(q[e], w1[e], a);
                    out[(size_t)b * P_TOT + c] = a;
                }
            }
        }
    }
}

extern "C" void kernel_launch(void* const* d_in, const int* in_sizes, int n_in,
                              void* d_out, int out_size, void* d_ws, size_t ws_size,
                              hipStream_t stream) {
    const float* feat = (const float*)d_in[0];
    const float* fcw  = (const float*)d_in[1];
    const float* fcb  = (const float*)d_in[2];
    const float* cb   = (const float*)d_in[3];
    const float* wgen = (const float*)d_in[4];
    float* out = (float*)d_out;

    float* qws   = (float*)d_ws;          // 1024 fp32
    float* lpart = qws + BATCH * EMB;     // 64 fp32

    k_embed_vq<<<BATCH, 256, 0, stream>>>(feat, fcw, fcb, cb, qws, lpart);

    const int colblocks = (P_TOT + 1023) / 1024;      // 1448
    k_gen<<<colblocks + 1, 256, 0, stream>>>(wgen, qws, lpart, out);
}